// Round 17
// baseline (66.884 us; speedup 1.0000x reference)
//
#include <hip/hip_runtime.h>

// Trilinear warp (SpatialTransformer): vol [B=2,D=160,H=192,W=160,C=2] f32,
// flow [B,D,H,W,3] f32 ('ij'). Output f32, same shape as vol.
//
// R16 (64.4us): DMA staging + pre-barrier precompute + branchless samples.
// VALU is the tallest pole (~57% busy at bench speed); largest remaining
// waste is the staging decode (5x magic-mul i->(lx,ly,lq) + 64b addr).
// R17: incremental carry-based decode (step +1024: lq+=4 mod12 carry ct,
// ly+=13+ct mod24 carry cy, lx+=3+cy; verified vs direct decode) + uniform
// (ox,oy,oz) hoisted to SGPR base + per-lane offset via v_mad_u32_u24.

constexpr int Bb = 2, Dd = 160, Hh = 192, Ww = 160;
constexpr int HW  = Hh * Ww;          // 30720
constexpr int VOX = Dd * HW;          // 4,915,200 voxels per batch

constexpr int TD = 8,  TH = 16, TW = 16;   // output tile (2048 voxels)
constexpr int RD = TD + 8;                 // 16  staged region (halo 4)
constexpr int RH = TH + 8;                 // 24
constexpr int RW = TW + 8;                 // 24
constexpr int RWP = 24;                    // UNPADDED row stride (float2) — linear DMA
constexpr int QROW = RW / 2;               // 12 float4 quads per row
constexpr int NQ = RD * RH * QROW;         // 4608 staged quads (i*16B linear)
constexpr int ND = Dd / TD, NH = Hh / TH, NW = Ww / TW;   // 20, 12, 10
constexpr int NBLK = Bb * ND * NH * NW;                   // 4800
constexpr int BLOCK = 1024;                // 16 waves; 2 voxels per thread
constexpr size_t LDS_BYTES = (size_t)NQ * 16;             // 73728 B

// Pre-barrier per-sample state: 8 LDS float2-indices + 8 weights + ok.
// Named scalar fields (rule #20: no runtime-indexed arrays).
struct PreS {
    int   p000, p001, p010, p011, p100, p101, p110, p111;
    float w000, w001, w010, w011, w100, w101, w110, w111;
    bool  ok;
};

// Coordinate/weight/address math — depends ONLY on flow + block constants.
// Identical numeric op order to R14/R16 (med3 int path, xy*z products).
__device__ __forceinline__ PreS pre_sample(int ox, int oy, int oz,
                                           int dd, int hh, int ww,
                                           float fx, float fy, float fz)
{
    PreS s;
    const float mn3 = fminf(fminf(fx, fy), fz);   // v_min3_f32
    const float mx3 = fmaxf(fmaxf(fx, fy), fz);   // v_max3_f32
    s.ok = (mn3 >= -4.0f) & (mx3 < 4.0f);

    const float lxf = (float)dd + fx;
    const float lyf = (float)hh + fy;
    const float lzf = (float)ww + fz;

    const int i0x = min(max(__float2int_rd(lxf), 0), Dd - 1);  // v_med3
    const int i0y = min(max(__float2int_rd(lyf), 0), Hh - 1);
    const int i0z = min(max(__float2int_rd(lzf), 0), Ww - 1);
    const int i1x = min(i0x + 1, Dd - 1);
    const int i1y = min(i0y + 1, Hh - 1);
    const int i1z = min(i0z + 1, Ww - 1);

    const float d1x = (float)i1x - lxf, d0x = 1.0f - d1x;
    const float d1y = (float)i1y - lyf, d0y = 1.0f - d1y;
    const float d1z = (float)i1z - lzf, d0z = 1.0f - d1z;

    // region-local coords, UNCLAMPED (ok lanes in-bounds by the flow test;
    // not-ok lanes may go OOB in LDS: HW returns 0, fixup overwrites)
    const int a0x = i0x - ox, a1x = i1x - ox;
    const int a0y = i0y - oy, a1y = i1y - oy;
    const int a0z = i0z - oz, a1z = i1z - oz;

    const int r00 = (a0x * RH + a0y) * RWP;
    const int r01 = (a0x * RH + a1y) * RWP;
    const int r10 = (a1x * RH + a0y) * RWP;
    const int r11 = (a1x * RH + a1y) * RWP;
    s.p000 = r00 + a0z;  s.p001 = r00 + a1z;
    s.p010 = r01 + a0z;  s.p011 = r01 + a1z;
    s.p100 = r10 + a0z;  s.p101 = r10 + a1z;
    s.p110 = r11 + a0z;  s.p111 = r11 + a1z;

    const float xy00 = d1x * d1y, xy01 = d1x * d0y;
    const float xy10 = d0x * d1y, xy11 = d0x * d0y;
    s.w000 = xy00 * d1z;  s.w001 = xy00 * d0z;
    s.w010 = xy01 * d1z;  s.w011 = xy01 * d0z;
    s.w100 = xy10 * d1z;  s.w101 = xy10 * d0z;
    s.w110 = xy11 * d1z;  s.w111 = xy11 * d0z;
    return s;
}

// Exact reference math + global gathers — rare out-of-region lanes only.
__device__ __forceinline__ void sample_global(const float2* __restrict__ v2,
                                              int d, int h, int w,
                                              float fx, float fy, float fz,
                                              float& oxv, float& oyv)
{
    const float mx = (float)(Dd - 1), my = (float)(Hh - 1), mz = (float)(Ww - 1);
    const float lxf = (float)d + fx;
    const float lyf = (float)h + fy;
    const float lzf = (float)w + fz;

    const float l0x = fminf(fmaxf(floorf(lxf), 0.0f), mx);
    const float l0y = fminf(fmaxf(floorf(lyf), 0.0f), my);
    const float l0z = fminf(fmaxf(floorf(lzf), 0.0f), mz);
    const float l1x = fminf(l0x + 1.0f, mx);
    const float l1y = fminf(l0y + 1.0f, my);
    const float l1z = fminf(l0z + 1.0f, mz);

    const float d1x = l1x - lxf, d0x = 1.0f - d1x;
    const float d1y = l1y - lyf, d0y = 1.0f - d1y;
    const float d1z = l1z - lzf, d0z = 1.0f - d1z;

    const int i0x = (int)l0x, i1x = (int)l1x;
    const int i0y = (int)l0y, i1y = (int)l1y;
    const int i0z = (int)l0z, i1z = (int)l1z;

    const int rx0 = i0x * HW, rx1 = i1x * HW;
    const int ry0 = i0y * Ww, ry1 = i1y * Ww;
    const float2 c000 = v2[rx0 + ry0 + i0z], c001 = v2[rx0 + ry0 + i1z];
    const float2 c010 = v2[rx0 + ry1 + i0z], c011 = v2[rx0 + ry1 + i1z];
    const float2 c100 = v2[rx1 + ry0 + i0z], c101 = v2[rx1 + ry0 + i1z];
    const float2 c110 = v2[rx1 + ry1 + i0z], c111 = v2[rx1 + ry1 + i1z];

    const float w000 = d1x * d1y * d1z, w001 = d1x * d1y * d0z;
    const float w010 = d1x * d0y * d1z, w011 = d1x * d0y * d0z;
    const float w100 = d0x * d1y * d1z, w101 = d0x * d1y * d0z;
    const float w110 = d0x * d0y * d1z, w111 = d0x * d0y * d0z;

    oxv = w000 * c000.x;
    oyv = w000 * c000.y;
    oxv = fmaf(w001, c001.x, oxv);  oyv = fmaf(w001, c001.y, oyv);
    oxv = fmaf(w010, c010.x, oxv);  oyv = fmaf(w010, c010.y, oyv);
    oxv = fmaf(w011, c011.x, oxv);  oyv = fmaf(w011, c011.y, oyv);
    oxv = fmaf(w100, c100.x, oxv);  oyv = fmaf(w100, c100.y, oyv);
    oxv = fmaf(w101, c101.x, oxv);  oyv = fmaf(w101, c101.y, oyv);
    oxv = fmaf(w110, c110.x, oxv);  oyv = fmaf(w110, c110.y, oyv);
    oxv = fmaf(w111, c111.x, oxv);  oyv = fmaf(w111, c111.y, oyv);
}

__global__ __launch_bounds__(BLOCK, 8)   // 8 waves/EU => VGPR<=64 => 2 blocks/CU
void SpatialTransformer_44418551776013_kernel(const float* __restrict__ vol,
                                              const float* __restrict__ flow,
                                              float* __restrict__ out)
{
    extern __shared__ float2 sv[];   // [RD][RH][RWP], linear
    const int tid = threadIdx.x;

    // bijective XCD swizzle (NBLK % 8 == 0). Validated: FETCH 222 -> 132 MB.
    constexpr int CPX = NBLK / 8;    // 600
    int bid = (int)(blockIdx.x % 8) * CPX + (int)(blockIdx.x / 8);

    const int bw = bid % NW;  bid /= NW;
    const int bh = bid % NH;  bid /= NH;
    const int bd = bid % ND;
    const int b  = bid / ND;
    const int d0 = bd * TD, h0 = bh * TH, w0 = bw * TW;

    // staged region = clip(tile +- 4); block-uniform -> SGPRs
    const int ox = max(0, d0 - 4), oy = max(0, h0 - 4), oz = max(0, w0 - 4);
    const int ex = min(Dd - 1, d0 + TD + 3) - ox + 1;   // <= RD
    const int ey = min(Hh - 1, h0 + TH + 3) - oy + 1;   // <= RH
    const int ez = min(Ww - 1, w0 + TW + 3) - oz + 1;   // <= RW, even
    const int qz = ez >> 1;

    // compute mapping: (td, th, tw2); thread owns voxels (d,h,w) & (d,h,w+1)
    const int tw2 = tid & 7;             // w-pair index 0..7
    const int th  = (tid >> 3) & 15;     // 0..15
    const int td  = tid >> 7;            // 0..7
    const int h = h0 + th;
    const int w = w0 + 2 * tw2;
    const int d = d0 + td;
    const int gidx = ((b * Dd + d) * Hh + h) * Ww + w;   // even

    // flow for BOTH voxels = 6 contiguous floats (issued FIRST — oldest in
    // the vmcnt queue, so consuming them waits only vmcnt(5): DMAs in flight)
    const float4 fA = *reinterpret_cast<const float4*>(flow + (size_t)gidx * 3);
    const float2 fB = *reinterpret_cast<const float2*>(flow + (size_t)gidx * 3 + 4);
    // voxel 1: (fA.x, fA.y, fA.z)   voxel 2: (fA.w, fB.x, fB.y)

    const float2* __restrict__ v2 =
        reinterpret_cast<const float2*>(vol) + (size_t)b * VOX;

    // ---- stage region via global_load_lds DMA (16B/lane, linear dest) ----
    // Incremental decode: i = tid + k*1024; step +1024 in (lq,ly,lx) is
    // lq+=4 (mod 12, carry ct), ly+=13+ct (mod 24, carry cy), lx+=3+cy.
    // Uniform (ox,oy,oz) hoisted into SGPR base; per-lane offset = 2 mad24.
    {
        // k=0 decode (one magic-mul set)
        int lq = tid % QROW;
        const int t0 = tid / QROW;
        int ly = t0 % RH;
        int lx = t0 / RH;

        const float2* __restrict__ base =
            v2 + ((size_t)ox * HW + (size_t)oy * Ww + oz);   // block-uniform

        if ((ex == RD) & (ey == RH) & (ez == RW)) {   // interior: clamp-free
            #pragma unroll
            for (int k = 0; k < 5; ++k) {
                if (k < 4 || tid < NQ - 4 * BLOCK) {   // k=4: tid<512 (wave-uniform)
                    const int off = __mul24(lx, HW) + __mul24(ly, Ww) + 2 * lq;
                    __builtin_amdgcn_global_load_lds(
                        (const __attribute__((address_space(1))) void*)(base + off),
                        (__attribute__((address_space(3))) void*)
                            (sv + (size_t)2 * (tid + k * BLOCK)),
                        16, 0, 0);
                }
                // carry-based step to i + 1024 (dead after k=4 -> DCE)
                lq += 4;       const int ct = (lq >= QROW); lq -= ct ? QROW : 0;
                ly += 13 + ct; const int cy = (ly >= RH);   ly -= cy ? RH   : 0;
                lx += 3 + cy;
            }
        } else {                                       // edge: clamped source
            #pragma unroll
            for (int k = 0; k < 5; ++k) {
                if (k < 4 || tid < NQ - 4 * BLOCK) {
                    const int lxc = min(lx, ex - 1);
                    const int lyc = min(ly, ey - 1);
                    const int lqc = min(lq, qz - 1);
                    const int off = __mul24(lxc, HW) + __mul24(lyc, Ww) + 2 * lqc;
                    __builtin_amdgcn_global_load_lds(
                        (const __attribute__((address_space(1))) void*)(base + off),
                        (__attribute__((address_space(3))) void*)
                            (sv + (size_t)2 * (tid + k * BLOCK)),
                        16, 0, 0);
                }
                lq += 4;       const int ct = (lq >= QROW); lq -= ct ? QROW : 0;
                ly += 13 + ct; const int cy = (ly >= RH);   ly -= cy ? RH   : 0;
                lx += 3 + cy;
            }
        }
    }

    // ---- PRE-BARRIER: coordinate/weight/address math (no LDS dependency).
    const PreS s1 = pre_sample(ox, oy, oz, d, h, w,     fA.x, fA.y, fA.z);
    const PreS s2 = pre_sample(ox, oy, oz, d, h, w + 1, fA.w, fB.x, fB.y);

    __builtin_amdgcn_sched_barrier(0);   // pin precompute above the drain
    __syncthreads();                     // vmcnt(0) drain + s_barrier

    // ---- POST-BARRIER: 16 ds_reads + dual-chain FMA only ----
    const float2 a000 = sv[s1.p000], a001 = sv[s1.p001];
    const float2 a010 = sv[s1.p010], a011 = sv[s1.p011];
    const float2 a100 = sv[s1.p100], a101 = sv[s1.p101];
    const float2 a110 = sv[s1.p110], a111 = sv[s1.p111];
    const float2 b000 = sv[s2.p000], b001 = sv[s2.p001];
    const float2 b010 = sv[s2.p010], b011 = sv[s2.p011];
    const float2 b100 = sv[s2.p100], b101 = sv[s2.p101];
    const float2 b110 = sv[s2.p110], b111 = sv[s2.p111];

    float o1x = s1.w000 * a000.x;
    float o1y = s1.w000 * a000.y;
    o1x = fmaf(s1.w001, a001.x, o1x);  o1y = fmaf(s1.w001, a001.y, o1y);
    o1x = fmaf(s1.w010, a010.x, o1x);  o1y = fmaf(s1.w010, a010.y, o1y);
    o1x = fmaf(s1.w011, a011.x, o1x);  o1y = fmaf(s1.w011, a011.y, o1y);
    o1x = fmaf(s1.w100, a100.x, o1x);  o1y = fmaf(s1.w100, a100.y, o1y);
    o1x = fmaf(s1.w101, a101.x, o1x);  o1y = fmaf(s1.w101, a101.y, o1y);
    o1x = fmaf(s1.w110, a110.x, o1x);  o1y = fmaf(s1.w110, a110.y, o1y);
    o1x = fmaf(s1.w111, a111.x, o1x);  o1y = fmaf(s1.w111, a111.y, o1y);

    float o2x = s2.w000 * b000.x;
    float o2y = s2.w000 * b000.y;
    o2x = fmaf(s2.w001, b001.x, o2x);  o2y = fmaf(s2.w001, b001.y, o2y);
    o2x = fmaf(s2.w010, b010.x, o2x);  o2y = fmaf(s2.w010, b010.y, o2y);
    o2x = fmaf(s2.w011, b011.x, o2x);  o2y = fmaf(s2.w011, b011.y, o2y);
    o2x = fmaf(s2.w100, b100.x, o2x);  o2y = fmaf(s2.w100, b100.y, o2y);
    o2x = fmaf(s2.w101, b101.x, o2x);  o2y = fmaf(s2.w101, b101.y, o2y);
    o2x = fmaf(s2.w110, b110.x, o2x);  o2y = fmaf(s2.w110, b110.y, o2y);
    o2x = fmaf(s2.w111, b111.x, o2x);  o2y = fmaf(s2.w111, b111.y, o2y);

    // ---- deferred rare fixup (wave-uniform skip for ~all waves) ----
    if (!__all(s1.ok && s2.ok)) {
        if (!s1.ok) sample_global(v2, d, h, w,     fA.x, fA.y, fA.z, o1x, o1y);
        if (!s2.ok) sample_global(v2, d, h, w + 1, fA.w, fB.x, fB.y, o2x, o2y);
    }

    // both voxels' outputs are adjacent float2s -> one 16B-aligned store
    *reinterpret_cast<float4*>(reinterpret_cast<float2*>(out) + gidx) =
        make_float4(o1x, o1y, o2x, o2y);
}

extern "C" void kernel_launch(void* const* d_in, const int* in_sizes, int n_in,
                              void* d_out, int out_size, void* d_ws, size_t ws_size,
                              hipStream_t stream)
{
    const float* vol  = (const float*)d_in[0];   // [2,160,192,160,2] f32
    const float* flow = (const float*)d_in[1];   // [2,160,192,160,3] f32
    float* out = (float*)d_out;                  // [2,160,192,160,2] f32

    SpatialTransformer_44418551776013_kernel<<<NBLK, BLOCK, LDS_BYTES, stream>>>(vol, flow, out);
}